// Round 2
// baseline (19298.470 us; speedup 1.0000x reference)
//
#include <hip/hip_runtime.h>

#define SEQ_T 2048
#define DIN   16
#define HH    80
#define NG    320   // 4*H
#define BT    2     // batches per block
#define NBLK  256   // 256 * BT = 512 = BATCH

// Unified LDS layout (floats):
//   h1   : [0,160)        h1[b][j] = b*80+j
//   h2   : [160,320)
//   pL1  : [320,960)      pL1[b][r] = 320 + b*320 + r
//   pI2  : [960,1600)
//   pH2  : [1600,2240)
//   px   : [2240,2880)
//   bs1  : [2880,3200)
//   bs2  : [3200,3520)
#define O_H1   0
#define O_H2   160
#define O_PL1  320
#define O_PI2  960
#define O_PH2  1600
#define O_PX   2240
#define O_BS1  2880
#define O_BS2  3200
#define S_TOT  3520

__device__ __forceinline__ float rcp_fast(float x) { return __builtin_amdgcn_rcpf(x); }
__device__ __forceinline__ float sigm(float x)   { return rcp_fast(1.0f + __expf(-x)); }
__device__ __forceinline__ float tanh_f(float x) { return 1.0f - 2.0f * rcp_fast(1.0f + __expf(2.0f * x)); }

__global__
__attribute__((amdgpu_flat_work_group_size(512, 512)))
__attribute__((amdgpu_waves_per_eu(2, 2)))          // pin RA budget to 256 VGPR: weights MUST stay in regs
void lstm2_fused(
    const float* __restrict__ x,
    const float* __restrict__ W_ih1, const float* __restrict__ W_hh1,
    const float* __restrict__ b_ih1, const float* __restrict__ b_hh1,
    const float* __restrict__ W_ih2, const float* __restrict__ W_hh2,
    const float* __restrict__ b_ih2, const float* __restrict__ b_hh2,
    const float* __restrict__ W_d,   const float* __restrict__ b_d,
    float* __restrict__ out)
{
    __shared__ float S[S_TOT];

    const int t  = threadIdx.x;
    const int wv = t >> 6;
    const int b0 = blockIdx.x * BT;

    // ---- stage bias sums, zero h ----
    if (t < NG) { S[O_BS1 + t] = b_ih1[t] + b_hh1[t]; S[O_BS2 + t] = b_ih2[t] + b_hh2[t]; }
    if (t < 2*BT*HH) S[t] = 0.0f;   // h1 and h2

    // ---- persistent weight registers: 2 x 80 floats/thread ----
    float wa[HH], wb[HH];
    {
        const float4 *A, *B;
        if (wv < 5) {                 // threads 0..319: W_hh1 row t  +  W_ih2 row t
            A = (const float4*)(W_hh1 + (size_t)t * HH);
            B = (const float4*)(W_ih2 + (size_t)t * HH);
        } else if (wv < 7) {          // threads 320..447: W_hh2 rows 2i, 2i+1
            const int i = t - 320;
            A = (const float4*)(W_hh2 + (size_t)(2*i)   * HH);
            B = (const float4*)(W_hh2 + (size_t)(2*i+1) * HH);
        } else {                      // threads 448..511: W_hh2 row 256+l + W_ih1 rows 5l..5l+4
            const int l = t - 448;
            A = (const float4*)(W_hh2 + (size_t)(256+l) * HH);
            B = (const float4*)(W_ih1 + (size_t)(5*l)   * DIN);   // 5*16 = 80 contiguous floats
        }
        #pragma unroll
        for (int q = 0; q < HH/4; ++q) {
            float4 av = A[q], bv = B[q];
            wa[4*q+0]=av.x; wa[4*q+1]=av.y; wa[4*q+2]=av.z; wa[4*q+3]=av.w;
            wb[4*q+0]=bv.x; wb[4*q+1]=bv.y; wb[4*q+2]=bv.z; wb[4*q+3]=bv.w;
        }
    }

    // ---- update-role constants: 32-bit LDS offsets, not pointers ----
    const bool isUpd = (t < 2*HH*BT);       // 320
    int offA = 0, offB = 0, offBS = 0, offH = 0;
    bool isL1 = false;
    if (isUpd) {
        int idx = t;
        isL1 = (idx < HH*BT);               // < 160
        if (!isL1) idx -= HH*BT;
        const int bb = idx / HH;
        const int u  = idx - bb*HH;
        if (isL1) {
            offA = O_PL1 + bb*NG + u;  offB = O_PX  + bb*NG + u;
            offBS = O_BS1 + u;         offH = O_H1 + bb*HH + u;
        } else {
            offA = O_PI2 + bb*NG + u;  offB = O_PH2 + bb*NG + u;
            offBS = O_BS2 + u;         offH = O_H2 + bb*HH + u;
        }
    }
    float c_reg = 0.0f;

    __syncthreads();

    // Pipelined: iteration k computes L1 partials for t=k and L2 partials for t=k-1.
    #pragma unroll 1
    for (int k = 0; k <= SEQ_T; ++k) {
        // ================= P phase: register-resident GEMV partials =================
        if (wv < 5) {
            float a00=0.f,a01=0.f,a10=0.f,a11=0.f;
            #pragma unroll
            for (int j = 0; j < HH; ++j) {
                const float v0 = S[O_H1 + j], v1 = S[O_H1 + HH + j];   // LDS broadcast
                a00 += wa[j]*v0; a01 += wa[j]*v1;
                a10 += wb[j]*v0; a11 += wb[j]*v1;
            }
            S[O_PL1 +      t]=a00; S[O_PL1 + NG + t]=a01;
            S[O_PI2 +      t]=a10; S[O_PI2 + NG + t]=a11;
        } else if (wv < 7) {
            const int r0 = 2*(t-320), r1 = r0+1;
            float a00=0.f,a01=0.f,a10=0.f,a11=0.f;
            #pragma unroll
            for (int j = 0; j < HH; ++j) {
                const float v0 = S[O_H2 + j], v1 = S[O_H2 + HH + j];
                a00 += wa[j]*v0; a01 += wa[j]*v1;
                a10 += wb[j]*v0; a11 += wb[j]*v1;
            }
            S[O_PH2 +      r0]=a00; S[O_PH2 + NG + r0]=a01;
            S[O_PH2 +      r1]=a10; S[O_PH2 + NG + r1]=a11;
        } else {
            const int l = t - 448, r = 256 + l;
            float a0=0.f, a1=0.f;
            #pragma unroll
            for (int j = 0; j < HH; ++j) {
                a0 += wa[j]*S[O_H2 + j];
                a1 += wa[j]*S[O_H2 + HH + j];
            }
            S[O_PH2 + r]=a0; S[O_PH2 + NG + r]=a1;
            if (k < SEQ_T) {                        // x-projection for timestep k
                #pragma unroll
                for (int b = 0; b < BT; ++b) {
                    const float4* xp = (const float4*)(x + ((size_t)(b0+b)*SEQ_T + (size_t)k)*DIN);
                    float xv[DIN];
                    const float4 q0=xp[0], q1=xp[1], q2=xp[2], q3=xp[3];
                    xv[0]=q0.x; xv[1]=q0.y; xv[2]=q0.z; xv[3]=q0.w;
                    xv[4]=q1.x; xv[5]=q1.y; xv[6]=q1.z; xv[7]=q1.w;
                    xv[8]=q2.x; xv[9]=q2.y; xv[10]=q2.z; xv[11]=q2.w;
                    xv[12]=q3.x; xv[13]=q3.y; xv[14]=q3.z; xv[15]=q3.w;
                    #pragma unroll
                    for (int r5 = 0; r5 < 5; ++r5) {
                        float acc = 0.f;
                        #pragma unroll
                        for (int d = 0; d < DIN; ++d) acc += wb[16*r5+d]*xv[d];
                        S[O_PX + b*NG + 5*l + r5] = acc;
                    }
                }
            }
        }
        __syncthreads();
        // ================= U phase: gate nonlinearities + state update =================
        if (isUpd) {
            const bool active = isL1 ? (k < SEQ_T) : (k >= 1);
            if (active) {
                const float gi = S[offA       ] + S[offB       ] + S[offBS       ];
                const float gf = S[offA +   HH] + S[offB +   HH] + S[offBS +   HH];
                const float gg = S[offA + 2*HH] + S[offB + 2*HH] + S[offBS + 2*HH];
                const float go = S[offA + 3*HH] + S[offB + 3*HH] + S[offBS + 3*HH];
                const float iv = sigm(gi), fv = sigm(gf), gv = tanh_f(gg), ov = sigm(go);
                c_reg = fv*c_reg + iv*gv;
                S[offH] = ov * tanh_f(c_reg);
            }
        }
        __syncthreads();
    }

    // ---- dense head: out[b] = h2_last[b] . W_d + b_d ----
    if (t < BT) {
        float acc = b_d[0];
        #pragma unroll
        for (int u2 = 0; u2 < HH; ++u2) acc += W_d[u2] * S[O_H2 + t*HH + u2];
        out[b0 + t] = acc;
    }
}

extern "C" void kernel_launch(void* const* d_in, const int* in_sizes, int n_in,
                              void* d_out, int out_size, void* d_ws, size_t ws_size,
                              hipStream_t stream) {
    const float* x     = (const float*)d_in[0];
    const float* W_ih1 = (const float*)d_in[1];
    const float* W_hh1 = (const float*)d_in[2];
    const float* b_ih1 = (const float*)d_in[3];
    const float* b_hh1 = (const float*)d_in[4];
    const float* W_ih2 = (const float*)d_in[5];
    const float* W_hh2 = (const float*)d_in[6];
    const float* b_ih2 = (const float*)d_in[7];
    const float* b_hh2 = (const float*)d_in[8];
    const float* W_d   = (const float*)d_in[9];
    const float* b_d   = (const float*)d_in[10];

    lstm2_fused<<<NBLK, 512, 0, stream>>>(x, W_ih1, W_hh1, b_ih1, b_hh1,
                                          W_ih2, W_hh2, b_ih2, b_hh2,
                                          W_d, b_d, (float*)d_out);
}

// Round 3
// 9516.721 us; speedup vs baseline: 2.0278x; 2.0278x over previous
//
#include <hip/hip_runtime.h>

#define SEQ_T 2048
#define DIN   16
#define HH    80
#define NG    320   // 4*H
#define BT    2     // batches per block
#define NBLK  256   // 256 * BT = 512 = BATCH
#define NTHR  1024

// Unified LDS layout (floats)
#define O_H1   0
#define O_H2   160
#define O_PL1  320
#define O_PI2  960
#define O_PH2  1600
#define O_PX   2240
#define O_BS1  2880
#define O_BS2  3200
#define S_TOT  3520

__device__ __forceinline__ float rcp_fast(float x) { return __builtin_amdgcn_rcpf(x); }
__device__ __forceinline__ float sigm(float x)   { return rcp_fast(1.0f + __expf(-x)); }
__device__ __forceinline__ float tanh_f(float x) { return 1.0f - 2.0f * rcp_fast(1.0f + __expf(2.0f * x)); }
__device__ __forceinline__ float d4(float4 w, float4 v, float a) {
    return fmaf(w.x, v.x, fmaf(w.y, v.y, fmaf(w.z, v.z, fmaf(w.w, v.w, a))));
}

// One q-chunk of the 80-long dot product, both batch columns.
// Named float4 weights => guaranteed SSA/VGPR (no alloca).
#define DOTQ(q) { \
    const float4 u0 = *(const float4*)&S[hbase +      4*(q)]; \
    const float4 u1 = *(const float4*)&S[hbase + HH + 4*(q)]; \
    a0 = d4(w##q, u0, a0); \
    a1 = d4(w##q, u1, a1); }

// x-projection: 5 rows of 16 (w0..w19), one batch column
#define XPROJ(base, xa, xb, xc, xd) { \
    S[(base)+0] = d4(w3,  xd, d4(w2,  xc, d4(w1,  xb, d4(w0,  xa, 0.f)))); \
    S[(base)+1] = d4(w7,  xd, d4(w6,  xc, d4(w5,  xb, d4(w4,  xa, 0.f)))); \
    S[(base)+2] = d4(w11, xd, d4(w10, xc, d4(w9,  xb, d4(w8,  xa, 0.f)))); \
    S[(base)+3] = d4(w15, xd, d4(w14, xc, d4(w13, xb, d4(w12, xa, 0.f)))); \
    S[(base)+4] = d4(w19, xd, d4(w18, xc, d4(w17, xb, d4(w16, xa, 0.f)))); }

__global__
__attribute__((amdgpu_flat_work_group_size(NTHR, NTHR)))
__attribute__((amdgpu_waves_per_eu(4, 4)))   // 128-VGPR budget, 16 waves/CU, 1 block/CU
void lstm2_fused(
    const float* __restrict__ x,
    const float* __restrict__ W_ih1, const float* __restrict__ W_hh1,
    const float* __restrict__ b_ih1, const float* __restrict__ b_hh1,
    const float* __restrict__ W_ih2, const float* __restrict__ W_hh2,
    const float* __restrict__ b_ih2, const float* __restrict__ b_hh2,
    const float* __restrict__ W_d,   const float* __restrict__ b_d,
    float* __restrict__ out)
{
    __shared__ __align__(16) float S[S_TOT];

    const int t  = threadIdx.x;
    const int wv = t >> 6;
    const int b0 = blockIdx.x * BT;

    // ---- stage bias sums, zero h1/h2 ----
    if (t < NG) { S[O_BS1 + t] = b_ih1[t] + b_hh1[t]; S[O_BS2 + t] = b_ih2[t] + b_hh2[t]; }
    if (t < 2*BT*HH) S[t] = 0.0f;

    // ---- persistent weights: ONE 80-float row per thread, in 20 NAMED float4s ----
    float4 w0,w1,w2,w3,w4,w5,w6,w7,w8,w9,w10,w11,w12,w13,w14,w15,w16,w17,w18,w19;
    {
        const float4* P;
        if      (wv <  5) P = (const float4*)W_hh1 + 20*t;          // rows 0..319 of W_hh1
        else if (wv < 10) P = (const float4*)W_ih2 + 20*(t-320);    // rows 0..319 of W_ih2
        else if (wv < 15) P = (const float4*)W_hh2 + 20*(t-640);    // rows 0..319 of W_hh2
        else              P = (const float4*)W_ih1 + 20*(t-960);    // lane l: W_ih1 rows 5l..5l+4
        w0 =P[0];  w1 =P[1];  w2 =P[2];  w3 =P[3];  w4 =P[4];
        w5 =P[5];  w6 =P[6];  w7 =P[7];  w8 =P[8];  w9 =P[9];
        w10=P[10]; w11=P[11]; w12=P[12]; w13=P[13]; w14=P[14];
        w15=P[15]; w16=P[16]; w17=P[17]; w18=P[18]; w19=P[19];
    }

    // ---- P-phase constants ----
    const int hbase = (wv < 10) ? O_H1 : O_H2;   // Whh1/Wih2 consume h1; Whh2 consumes h2
    int off_p = 0;
    if      (wv <  5) off_p = O_PL1 + t;
    else if (wv < 10) off_p = O_PI2 + (t - 320);
    else if (wv < 15) off_p = O_PH2 + (t - 640);
    const int l = t - 960;                        // wave 15 only

    // ---- U-phase constants (threads 0..319) ----
    const bool isUpd = (t < 2*HH*BT);
    int offA = 0, offB = 0, offBS = 0, offH = 0;
    bool isL1 = false;
    if (isUpd) {
        int idx = t;
        isL1 = (idx < HH*BT);
        if (!isL1) idx -= HH*BT;
        const int bb = idx / HH;
        const int u  = idx - bb*HH;
        if (isL1) { offA = O_PL1 + bb*NG + u; offB = O_PX  + bb*NG + u; offBS = O_BS1 + u; offH = O_H1 + bb*HH + u; }
        else      { offA = O_PI2 + bb*NG + u; offB = O_PH2 + bb*NG + u; offBS = O_BS2 + u; offH = O_H2 + bb*HH + u; }
    }
    float c_reg = 0.0f;

    __syncthreads();

    // Pipelined: iteration k computes L1 partials for t=k and L2 partials for t=k-1.
    #pragma unroll 1
    for (int k = 0; k <= SEQ_T; ++k) {
        // ================= P phase =================
        if (wv < 15) {
            float a0 = 0.f, a1 = 0.f;
            DOTQ(0)  DOTQ(1)  DOTQ(2)  DOTQ(3)  DOTQ(4)
            DOTQ(5)  DOTQ(6)  DOTQ(7)  DOTQ(8)  DOTQ(9)
            DOTQ(10) DOTQ(11) DOTQ(12) DOTQ(13) DOTQ(14)
            DOTQ(15) DOTQ(16) DOTQ(17) DOTQ(18) DOTQ(19)
            S[off_p]      = a0;
            S[off_p + NG] = a1;
        } else if (k < SEQ_T) {
            // x-projection for timestep k (wave 15)
            const float4* xp0 = (const float4*)(x + ((size_t)(b0    )*SEQ_T + (size_t)k)*DIN);
            const float4* xp1 = (const float4*)(x + ((size_t)(b0 + 1)*SEQ_T + (size_t)k)*DIN);
            {
                const float4 xa = xp0[0], xb = xp0[1], xc = xp0[2], xd = xp0[3];
                XPROJ(O_PX + 5*l, xa, xb, xc, xd)
            }
            {
                const float4 xa = xp1[0], xb = xp1[1], xc = xp1[2], xd = xp1[3];
                XPROJ(O_PX + NG + 5*l, xa, xb, xc, xd)
            }
        }
        __syncthreads();
        // ================= U phase =================
        if (isUpd) {
            const bool active = isL1 ? (k < SEQ_T) : (k >= 1);
            if (active) {
                const float gi = S[offA       ] + S[offB       ] + S[offBS       ];
                const float gf = S[offA +   HH] + S[offB +   HH] + S[offBS +   HH];
                const float gg = S[offA + 2*HH] + S[offB + 2*HH] + S[offBS + 2*HH];
                const float go = S[offA + 3*HH] + S[offB + 3*HH] + S[offBS + 3*HH];
                const float iv = sigm(gi), fv = sigm(gf), gv = tanh_f(gg), ov = sigm(go);
                c_reg = fv*c_reg + iv*gv;
                S[offH] = ov * tanh_f(c_reg);
            }
        }
        __syncthreads();
    }

    // ---- dense head: out[b] = h2_last[b] . W_d + b_d ----
    if (t < BT) {
        float acc = b_d[0];
        #pragma unroll
        for (int u2 = 0; u2 < HH; ++u2) acc += W_d[u2] * S[O_H2 + t*HH + u2];
        out[b0 + t] = acc;
    }
}

extern "C" void kernel_launch(void* const* d_in, const int* in_sizes, int n_in,
                              void* d_out, int out_size, void* d_ws, size_t ws_size,
                              hipStream_t stream) {
    const float* x     = (const float*)d_in[0];
    const float* W_ih1 = (const float*)d_in[1];
    const float* W_hh1 = (const float*)d_in[2];
    const float* b_ih1 = (const float*)d_in[3];
    const float* b_hh1 = (const float*)d_in[4];
    const float* W_ih2 = (const float*)d_in[5];
    const float* W_hh2 = (const float*)d_in[6];
    const float* b_ih2 = (const float*)d_in[7];
    const float* b_hh2 = (const float*)d_in[8];
    const float* W_d   = (const float*)d_in[9];
    const float* b_d   = (const float*)d_in[10];

    lstm2_fused<<<NBLK, NTHR, 0, stream>>>(x, W_ih1, W_hh1, b_ih1, b_hh1,
                                           W_ih2, W_hh2, b_ih2, b_hh2,
                                           W_d, b_d, (float*)d_out);
}

// Round 5
// 3853.307 us; speedup vs baseline: 5.0083x; 2.4698x over previous
//
#include <hip/hip_runtime.h>

#define SEQ_T 2048
#define DIN   16
#define HH    80
#define NG    320   // 4*H
#define BT    2     // batches per block
#define NBLK  256   // 256 * BT = 512 = BATCH
#define NTHR  512

// Unified LDS layout (floats)
#define O_H1   0
#define O_H2   160
#define O_PL1  320
#define O_PI2  960
#define O_PH2  1600
#define O_PX   2240
#define O_BS1  2880
#define O_BS2  3200
#define S_TOT  3520

__device__ __forceinline__ float rcp_fast(float x) { return __builtin_amdgcn_rcpf(x); }
__device__ __forceinline__ float sigm(float x)   { return rcp_fast(1.0f + __expf(-x)); }
__device__ __forceinline__ float tanh_f(float x) { return 1.0f - 2.0f * rcp_fast(1.0f + __expf(2.0f * x)); }
__device__ __forceinline__ float d4(float4 w, float4 v, float a) {
    return fmaf(w.x, v.x, fmaf(w.y, v.y, fmaf(w.z, v.z, fmaf(w.w, v.w, a))));
}

// Anti-remat pin: value def becomes opaque asm output -> RA must keep it in a VGPR,
// cannot sink the original loop-invariant global load into the loop.
#define PIN4(v) asm volatile("" : "+v"(v.x), "+v"(v.y), "+v"(v.z), "+v"(v.w))

// One 16-byte chunk of the 80-long dot product: A-row and B-row x both batch columns.
// h loads shared between A and B dots (40 ds_read_b128 per 320 FMAs).
#define DOTAB(q) { \
    const float4 u0 = *(const float4*)&S[hb +      4*(q)]; \
    const float4 u1 = *(const float4*)&S[hb + HH + 4*(q)]; \
    a00 = d4(A##q, u0, a00); a01 = d4(A##q, u1, a01); \
    a10 = d4(B##q, u0, a10); a11 = d4(B##q, u1, a11); }

// A-row only (wave 7)
#define DOTA(q) { \
    const float4 u0 = *(const float4*)&S[O_H2 +      4*(q)]; \
    const float4 u1 = *(const float4*)&S[O_H2 + HH + 4*(q)]; \
    a00 = d4(A##q, u0, a00); a01 = d4(A##q, u1, a01); }

// x-projection: B0..B19 = 5 rows of 16 weights; one batch column
#define XPROJ(base, xa, xb, xc, xd) { \
    S[(base)+0] = d4(B3,  xd, d4(B2,  xc, d4(B1,  xb, d4(B0,  xa, 0.f)))); \
    S[(base)+1] = d4(B7,  xd, d4(B6,  xc, d4(B5,  xb, d4(B4,  xa, 0.f)))); \
    S[(base)+2] = d4(B11, xd, d4(B10, xc, d4(B9,  xb, d4(B8,  xa, 0.f)))); \
    S[(base)+3] = d4(B15, xd, d4(B14, xc, d4(B13, xb, d4(B12, xa, 0.f)))); \
    S[(base)+4] = d4(B19, xd, d4(B18, xc, d4(B17, xb, d4(B16, xa, 0.f)))); }

__global__
__attribute__((amdgpu_flat_work_group_size(NTHR, NTHR)))
__attribute__((amdgpu_waves_per_eu(2, 2)))   // 256-VGPR budget: 160 pinned weights + working set fit
void lstm2_fused(
    const float* __restrict__ x,
    const float* __restrict__ W_ih1, const float* __restrict__ W_hh1,
    const float* __restrict__ b_ih1, const float* __restrict__ b_hh1,
    const float* __restrict__ W_ih2, const float* __restrict__ W_hh2,
    const float* __restrict__ b_ih2, const float* __restrict__ b_hh2,
    const float* __restrict__ W_d,   const float* __restrict__ b_d,
    float* __restrict__ out)
{
    __shared__ __align__(16) float S[S_TOT];

    const int t  = threadIdx.x;
    const int wv = t >> 6;
    const int b0 = blockIdx.x * BT;

    // ---- stage bias sums, zero h1/h2 ----
    if (t < NG) { S[O_BS1 + t] = b_ih1[t] + b_hh1[t]; S[O_BS2 + t] = b_ih2[t] + b_hh2[t]; }
    if (t < 2*BT*HH) S[t] = 0.0f;

    // ---- persistent weights: 2 x 80 floats/thread in 40 NAMED float4s, asm-pinned ----
    float4 A0,A1,A2,A3,A4,A5,A6,A7,A8,A9,A10,A11,A12,A13,A14,A15,A16,A17,A18,A19;
    float4 B0,B1,B2,B3,B4,B5,B6,B7,B8,B9,B10,B11,B12,B13,B14,B15,B16,B17,B18,B19;
    {
        const float4 *PA, *PB;
        if (wv < 5) {                 // threads 0..319: W_hh1 row t  +  W_ih2 row t
            PA = (const float4*)W_hh1 + 20*t;
            PB = (const float4*)W_ih2 + 20*t;
        } else if (wv < 7) {          // threads 320..447: W_hh2 rows 2i, 2i+1
            const int i = t - 320;
            PA = (const float4*)W_hh2 + 20*(2*i);
            PB = (const float4*)W_hh2 + 20*(2*i+1);
        } else {                      // threads 448..511: W_hh2 row 256+l + W_ih1 rows 5l..5l+4
            const int l7 = t - 448;
            PA = (const float4*)W_hh2 + 20*(256+l7);
            PB = (const float4*)W_ih1 + 20*l7;    // rows 5l..5l+4 = 80*l floats = 20*l float4  (R4 bug: was 5*l)
        }
        A0 =PA[0];  A1 =PA[1];  A2 =PA[2];  A3 =PA[3];  A4 =PA[4];
        A5 =PA[5];  A6 =PA[6];  A7 =PA[7];  A8 =PA[8];  A9 =PA[9];
        A10=PA[10]; A11=PA[11]; A12=PA[12]; A13=PA[13]; A14=PA[14];
        A15=PA[15]; A16=PA[16]; A17=PA[17]; A18=PA[18]; A19=PA[19];
        B0 =PB[0];  B1 =PB[1];  B2 =PB[2];  B3 =PB[3];  B4 =PB[4];
        B5 =PB[5];  B6 =PB[6];  B7 =PB[7];  B8 =PB[8];  B9 =PB[9];
        B10=PB[10]; B11=PB[11]; B12=PB[12]; B13=PB[13]; B14=PB[14];
        B15=PB[15]; B16=PB[16]; B17=PB[17]; B18=PB[18]; B19=PB[19];
        PIN4(A0);  PIN4(A1);  PIN4(A2);  PIN4(A3);  PIN4(A4);
        PIN4(A5);  PIN4(A6);  PIN4(A7);  PIN4(A8);  PIN4(A9);
        PIN4(A10); PIN4(A11); PIN4(A12); PIN4(A13); PIN4(A14);
        PIN4(A15); PIN4(A16); PIN4(A17); PIN4(A18); PIN4(A19);
        PIN4(B0);  PIN4(B1);  PIN4(B2);  PIN4(B3);  PIN4(B4);
        PIN4(B5);  PIN4(B6);  PIN4(B7);  PIN4(B8);  PIN4(B9);
        PIN4(B10); PIN4(B11); PIN4(B12); PIN4(B13); PIN4(B14);
        PIN4(B15); PIN4(B16); PIN4(B17); PIN4(B18); PIN4(B19);
    }

    // ---- P-phase constants ----
    const int hb = (wv < 5) ? O_H1 : O_H2;
    const int l  = t - 448;               // wave 7 lane row index

    // ---- U-phase constants (threads 0..319) ----
    const bool isUpd = (t < 2*HH*BT);
    int offA = 0, offB = 0, offBS = 0, offH = 0;
    bool isL1 = false;
    if (isUpd) {
        int idx = t;
        isL1 = (idx < HH*BT);
        if (!isL1) idx -= HH*BT;
        const int bb = idx / HH;
        const int u  = idx - bb*HH;
        if (isL1) { offA = O_PL1 + bb*NG + u; offB = O_PX  + bb*NG + u; offBS = O_BS1 + u; offH = O_H1 + bb*HH + u; }
        else      { offA = O_PI2 + bb*NG + u; offB = O_PH2 + bb*NG + u; offBS = O_BS2 + u; offH = O_H2 + bb*HH + u; }
    }
    float c_reg = 0.0f;

    __syncthreads();

    // Pipelined: iteration k computes L1 partials for t=k and L2 partials for t=k-1.
    #pragma unroll 1
    for (int k = 0; k <= SEQ_T; ++k) {
        // ================= P phase (weights in VGPRs, h via LDS broadcast) =================
        if (wv < 5) {
            float a00=0.f,a01=0.f,a10=0.f,a11=0.f;
            DOTAB(0)  DOTAB(1)  DOTAB(2)  DOTAB(3)  DOTAB(4)
            DOTAB(5)  DOTAB(6)  DOTAB(7)  DOTAB(8)  DOTAB(9)
            DOTAB(10) DOTAB(11) DOTAB(12) DOTAB(13) DOTAB(14)
            DOTAB(15) DOTAB(16) DOTAB(17) DOTAB(18) DOTAB(19)
            S[O_PL1 +      t]=a00; S[O_PL1 + NG + t]=a01;
            S[O_PI2 +      t]=a10; S[O_PI2 + NG + t]=a11;
        } else if (wv < 7) {
            const int r0 = 2*(t-320), r1 = r0+1;
            float a00=0.f,a01=0.f,a10=0.f,a11=0.f;
            DOTAB(0)  DOTAB(1)  DOTAB(2)  DOTAB(3)  DOTAB(4)
            DOTAB(5)  DOTAB(6)  DOTAB(7)  DOTAB(8)  DOTAB(9)
            DOTAB(10) DOTAB(11) DOTAB(12) DOTAB(13) DOTAB(14)
            DOTAB(15) DOTAB(16) DOTAB(17) DOTAB(18) DOTAB(19)
            S[O_PH2 +      r0]=a00; S[O_PH2 + NG + r0]=a01;
            S[O_PH2 +      r1]=a10; S[O_PH2 + NG + r1]=a11;
        } else {
            const int r = 256 + l;
            // issue x loads early; dot-product latency hides them
            const int kx = (k < SEQ_T) ? k : (SEQ_T-1);
            const float4* xp0 = (const float4*)(x + ((size_t)(b0    )*SEQ_T + (size_t)kx)*DIN);
            const float4* xp1 = (const float4*)(x + ((size_t)(b0 + 1)*SEQ_T + (size_t)kx)*DIN);
            const float4 xa0=xp0[0], xb0=xp0[1], xc0=xp0[2], xd0=xp0[3];
            const float4 xa1=xp1[0], xb1=xp1[1], xc1=xp1[2], xd1=xp1[3];
            float a00=0.f,a01=0.f;
            DOTA(0)  DOTA(1)  DOTA(2)  DOTA(3)  DOTA(4)
            DOTA(5)  DOTA(6)  DOTA(7)  DOTA(8)  DOTA(9)
            DOTA(10) DOTA(11) DOTA(12) DOTA(13) DOTA(14)
            DOTA(15) DOTA(16) DOTA(17) DOTA(18) DOTA(19)
            S[O_PH2 + r]=a00; S[O_PH2 + NG + r]=a01;
            if (k < SEQ_T) {
                XPROJ(O_PX + 5*l,      xa0, xb0, xc0, xd0)
                XPROJ(O_PX + NG + 5*l, xa1, xb1, xc1, xd1)
            }
        }
        __syncthreads();
        // ================= U phase =================
        if (isUpd) {
            const bool active = isL1 ? (k < SEQ_T) : (k >= 1);
            if (active) {
                const float gi = S[offA       ] + S[offB       ] + S[offBS       ];
                const float gf = S[offA +   HH] + S[offB +   HH] + S[offBS +   HH];
                const float gg = S[offA + 2*HH] + S[offB + 2*HH] + S[offBS + 2*HH];
                const float go = S[offA + 3*HH] + S[offB + 3*HH] + S[offBS + 3*HH];
                const float iv = sigm(gi), fv = sigm(gf), gv = tanh_f(gg), ov = sigm(go);
                c_reg = fv*c_reg + iv*gv;
                S[offH] = ov * tanh_f(c_reg);
            }
        }
        __syncthreads();
    }

    // ---- dense head: out[b] = h2_last[b] . W_d + b_d ----
    if (t < BT) {
        float acc = b_d[0];
        #pragma unroll
        for (int u2 = 0; u2 < HH; ++u2) acc += W_d[u2] * S[O_H2 + t*HH + u2];
        out[b0 + t] = acc;
    }
}

extern "C" void kernel_launch(void* const* d_in, const int* in_sizes, int n_in,
                              void* d_out, int out_size, void* d_ws, size_t ws_size,
                              hipStream_t stream) {
    const float* x     = (const float*)d_in[0];
    const float* W_ih1 = (const float*)d_in[1];
    const float* W_hh1 = (const float*)d_in[2];
    const float* b_ih1 = (const float*)d_in[3];
    const float* b_hh1 = (const float*)d_in[4];
    const float* W_ih2 = (const float*)d_in[5];
    const float* W_hh2 = (const float*)d_in[6];
    const float* b_ih2 = (const float*)d_in[7];
    const float* b_hh2 = (const float*)d_in[8];
    const float* W_d   = (const float*)d_in[9];
    const float* b_d   = (const float*)d_in[10];

    lstm2_fused<<<NBLK, NTHR, 0, stream>>>(x, W_ih1, W_hh1, b_ih1, b_hh1,
                                           W_ih2, W_hh2, b_ih2, b_hh2,
                                           W_d, b_d, (float*)d_out);
}

// Round 6
// 2793.761 us; speedup vs baseline: 6.9077x; 1.3793x over previous
//
#include <hip/hip_runtime.h>

#define SEQ_T 2048
#define DIN   16
#define HH    80
#define NG    320   // 4*H
#define NBLK  512   // BT=1: one batch element per block
#define NTHR  512

// fp32 LDS layout (floats)
#define O_PL1  0
#define O_PI2  320
#define O_PH2  640
#define O_PX   960
#define O_BS1  1280
#define O_BS2  1600
#define S_TOT  1920

typedef _Float16 h2v __attribute__((ext_vector_type(2)));

__device__ __forceinline__ float rcp_fast(float x) { return __builtin_amdgcn_rcpf(x); }
__device__ __forceinline__ float sigm(float x)   { return rcp_fast(1.0f + __expf(-x)); }
__device__ __forceinline__ float tanh_f(float x) { return 1.0f - 2.0f * rcp_fast(1.0f + __expf(2.0f * x)); }

// v_dot2_f32_f16: acc += w.lo*h.lo + w.hi*h.hi (fp32 accumulate), full VALU rate
static __device__ __forceinline__ float fdot2f(float w, float h, float acc) {
#if __has_builtin(__builtin_amdgcn_fdot2)
    return __builtin_amdgcn_fdot2(__builtin_bit_cast(h2v, w), __builtin_bit_cast(h2v, h), acc, false);
#else
    float r = acc;
    asm("v_dot2_f32_f16 %0, %1, %2, %0" : "+v"(r) : "v"(w), "v"(h));
    return r;
#endif
}

// pack two fp32 into f16x2 (RNE via scalar casts), return as float bit-container
static __device__ __forceinline__ float pk2(float a, float b) {
    h2v v; v.x = (_Float16)a; v.y = (_Float16)b;
    return __builtin_bit_cast(float, v);
}

// Anti-remat pin (R5-proven): opaque asm def -> RA cannot sink the global load into the loop.
#define PIN4(v) asm volatile("" : "+v"(v.x), "+v"(v.y), "+v"(v.z), "+v"(v.w))

// load 16 fp32 weights -> one float4 of 8 packed f16 pairs, for rows A and B
#define LDW(q) { \
    const float4 a = PA[2*(q)], b = PA[2*(q)+1]; \
    WA##q = make_float4(pk2(a.x,a.y), pk2(a.z,a.w), pk2(b.x,b.y), pk2(b.z,b.w)); \
    const float4 c = PB[2*(q)], d = PB[2*(q)+1]; \
    WB##q = make_float4(pk2(c.x,c.y), pk2(c.z,c.w), pk2(d.x,d.y), pk2(d.z,d.w)); }

// one 8-element h chunk (16 B of f16), rows A and B: 8 dot2 = 16 MACs
#define DOT2Q(q) { \
    const float4 hf = *(const float4*)(Hp + 8*(q)); \
    a0 = fdot2f(WA##q.x, hf.x, a0); a0 = fdot2f(WA##q.y, hf.y, a0); \
    a0 = fdot2f(WA##q.z, hf.z, a0); a0 = fdot2f(WA##q.w, hf.w, a0); \
    a1 = fdot2f(WB##q.x, hf.x, a1); a1 = fdot2f(WB##q.y, hf.y, a1); \
    a1 = fdot2f(WB##q.z, hf.z, a1); a1 = fdot2f(WB##q.w, hf.w, a1); }

// A-row only (wave 7)
#define DOT1Q(q) { \
    const float4 hf = *(const float4*)(Hp + 8*(q)); \
    a0 = fdot2f(WA##q.x, hf.x, a0); a0 = fdot2f(WA##q.y, hf.y, a0); \
    a0 = fdot2f(WA##q.z, hf.z, a0); a0 = fdot2f(WA##q.w, hf.w, a0); }

// x-projection row: 16 weights (two float4 of pairs) . x (8 pairs)
#define XROW(r5, Wa, Wb) { \
    float ax = 0.f; \
    ax = fdot2f(Wa.x, xi0, ax); ax = fdot2f(Wa.y, xi1, ax); \
    ax = fdot2f(Wa.z, xi2, ax); ax = fdot2f(Wa.w, xi3, ax); \
    ax = fdot2f(Wb.x, xi4, ax); ax = fdot2f(Wb.y, xi5, ax); \
    ax = fdot2f(Wb.z, xi6, ax); ax = fdot2f(Wb.w, xi7, ax); \
    S[O_PX + 5*l + (r5)] = ax; }

__global__
__attribute__((amdgpu_flat_work_group_size(NTHR, NTHR)))
__attribute__((amdgpu_waves_per_eu(4, 4)))   // 128-VGPR cap -> 16 waves/CU = 2 blocks/CU (bubble overlap)
void lstm2_fused(
    const float* __restrict__ x,
    const float* __restrict__ W_ih1, const float* __restrict__ W_hh1,
    const float* __restrict__ b_ih1, const float* __restrict__ b_hh1,
    const float* __restrict__ W_ih2, const float* __restrict__ W_hh2,
    const float* __restrict__ b_ih2, const float* __restrict__ b_hh2,
    const float* __restrict__ W_d,   const float* __restrict__ b_d,
    float* __restrict__ out)
{
    __shared__ float S[S_TOT];
    __shared__ __align__(16) _Float16 Hh1[HH];
    __shared__ __align__(16) _Float16 Hh2[HH];

    const int t  = threadIdx.x;
    const int wv = t >> 6;
    const int b0 = blockIdx.x;          // BT=1

    // ---- stage bias sums, zero h1/h2 ----
    if (t < NG) { S[O_BS1 + t] = b_ih1[t] + b_hh1[t]; S[O_BS2 + t] = b_ih2[t] + b_hh2[t]; }
    if (t < HH)            Hh1[t]      = (_Float16)0.f;
    else if (t < 2*HH)     Hh2[t - HH] = (_Float16)0.f;

    // ---- persistent weights: 2 rows x 80 f16/thread in 20 NAMED float4s (80 VGPRs), pinned ----
    float4 WA0,WA1,WA2,WA3,WA4,WA5,WA6,WA7,WA8,WA9;
    float4 WB0,WB1,WB2,WB3,WB4,WB5,WB6,WB7,WB8,WB9;
    {
        const float4 *PA, *PB;
        if (wv < 5) {                 // threads 0..319: W_hh1 row t  +  W_ih2 row t
            PA = (const float4*)W_hh1 + 20*t;
            PB = (const float4*)W_ih2 + 20*t;
        } else if (wv < 7) {          // threads 320..447: W_hh2 rows 2i, 2i+1
            const int i = t - 320;
            PA = (const float4*)W_hh2 + 20*(2*i);
            PB = (const float4*)W_hh2 + 20*(2*i+1);
        } else {                      // threads 448..511: W_hh2 row 256+l + W_ih1 rows 5l..5l+4
            const int l7 = t - 448;
            PA = (const float4*)W_hh2 + 20*(256+l7);
            PB = (const float4*)W_ih1 + 20*l7;    // 80*l floats = 20*l float4
        }
        LDW(0) LDW(1) LDW(2) LDW(3) LDW(4) LDW(5) LDW(6) LDW(7) LDW(8) LDW(9)
        PIN4(WA0); PIN4(WA1); PIN4(WA2); PIN4(WA3); PIN4(WA4);
        PIN4(WA5); PIN4(WA6); PIN4(WA7); PIN4(WA8); PIN4(WA9);
        PIN4(WB0); PIN4(WB1); PIN4(WB2); PIN4(WB3); PIN4(WB4);
        PIN4(WB5); PIN4(WB6); PIN4(WB7); PIN4(WB8); PIN4(WB9);
    }

    // ---- P-phase constants ----
    const _Float16* Hp = (wv < 5) ? Hh1 : Hh2;   // Whh1/Wih2 consume h1; Whh2 consumes h2
    const int l = t - 448;                        // wave 7 lane index

    // ---- U-phase constants (threads 0..159: one (layer,unit) each; BT=1) ----
    const bool isUpd = (t < 2*HH);
    const bool isL1  = (t < HH);
    int offA = 0, offB = 0, offBS = 0;
    _Float16* Hdst = nullptr;
    if (isUpd) {
        const int u = isL1 ? t : (t - HH);
        if (isL1) { offA = O_PL1 + u; offB = O_PX  + u; offBS = O_BS1 + u; Hdst = &Hh1[u]; }
        else      { offA = O_PI2 + u; offB = O_PH2 + u; offBS = O_BS2 + u; Hdst = &Hh2[u]; }
    }
    float c_reg = 0.0f;

    __syncthreads();

    // Pipelined: iteration k computes L1 partials for t=k and L2 partials for t=k-1.
    #pragma unroll 1
    for (int k = 0; k <= SEQ_T; ++k) {
        // ================= P phase: f16x2 dot2, weights in VGPRs =================
        if (wv < 7) {
            float a0 = 0.f, a1 = 0.f;
            DOT2Q(0) DOT2Q(1) DOT2Q(2) DOT2Q(3) DOT2Q(4)
            DOT2Q(5) DOT2Q(6) DOT2Q(7) DOT2Q(8) DOT2Q(9)
            if (wv < 5) { S[O_PL1 + t] = a0; S[O_PI2 + t] = a1; }
            else        { const int i = t - 320; S[O_PH2 + 2*i] = a0; S[O_PH2 + 2*i + 1] = a1; }
        } else {
            // wave 7: W_hh2 row 256+l over h2, plus x-projection
            const int kx = (k < SEQ_T) ? k : (SEQ_T - 1);
            const float4* xp = (const float4*)(x + ((size_t)b0*SEQ_T + (size_t)kx)*DIN);
            const float4 q0 = xp[0], q1 = xp[1], q2 = xp[2], q3 = xp[3];
            float a0 = 0.f;
            DOT1Q(0) DOT1Q(1) DOT1Q(2) DOT1Q(3) DOT1Q(4)
            DOT1Q(5) DOT1Q(6) DOT1Q(7) DOT1Q(8) DOT1Q(9)
            S[O_PH2 + 256 + l] = a0;
            if (k < SEQ_T) {
                const float xi0 = pk2(q0.x,q0.y), xi1 = pk2(q0.z,q0.w),
                            xi2 = pk2(q1.x,q1.y), xi3 = pk2(q1.z,q1.w),
                            xi4 = pk2(q2.x,q2.y), xi5 = pk2(q2.z,q2.w),
                            xi6 = pk2(q3.x,q3.y), xi7 = pk2(q3.z,q3.w);
                XROW(0, WB0, WB1) XROW(1, WB2, WB3) XROW(2, WB4, WB5)
                XROW(3, WB6, WB7) XROW(4, WB8, WB9)
            }
        }
        __syncthreads();
        // ================= U phase =================
        if (isUpd) {
            const bool active = isL1 ? (k < SEQ_T) : (k >= 1);
            if (active) {
                const float gi = S[offA         ] + S[offB         ] + S[offBS         ];
                const float gf = S[offA +     HH] + S[offB +     HH] + S[offBS +     HH];
                const float gg = S[offA + 2*HH  ] + S[offB + 2*HH  ] + S[offBS + 2*HH  ];
                const float go = S[offA + 3*HH  ] + S[offB + 3*HH  ] + S[offBS + 3*HH  ];
                const float iv = sigm(gi), fv = sigm(gf), gv = tanh_f(gg), ov = sigm(go);
                c_reg = fv*c_reg + iv*gv;
                *Hdst = (_Float16)(ov * tanh_f(c_reg));
            }
        }
        __syncthreads();
    }

    // ---- dense head: out[b0] = h2_last . W_d + b_d ----
    if (t == 0) {
        float acc = b_d[0];
        #pragma unroll
        for (int u2 = 0; u2 < HH; ++u2) acc += W_d[u2] * (float)Hh2[u2];
        out[b0] = acc;
    }
}

extern "C" void kernel_launch(void* const* d_in, const int* in_sizes, int n_in,
                              void* d_out, int out_size, void* d_ws, size_t ws_size,
                              hipStream_t stream) {
    const float* x     = (const float*)d_in[0];
    const float* W_ih1 = (const float*)d_in[1];
    const float* W_hh1 = (const float*)d_in[2];
    const float* b_ih1 = (const float*)d_in[3];
    const float* b_hh1 = (const float*)d_in[4];
    const float* W_ih2 = (const float*)d_in[5];
    const float* W_hh2 = (const float*)d_in[6];
    const float* b_ih2 = (const float*)d_in[7];
    const float* b_hh2 = (const float*)d_in[8];
    const float* W_d   = (const float*)d_in[9];
    const float* b_d   = (const float*)d_in[10];

    lstm2_fused<<<NBLK, NTHR, 0, stream>>>(x, W_ih1, W_hh1, b_ih1, b_hh1,
                                           W_ih2, W_hh2, b_ih2, b_hh2,
                                           W_d, b_d, (float*)d_out);
}